// Round 7
// baseline (300.011 us; speedup 1.0000x reference)
//
#include <hip/hip_runtime.h>
#include <hip/hip_bf16.h>
#include <stdint.h>

// Problem constants (from reference)
static constexpr int V_N = 50000;
static constexpr int E_N = 10000;
static constexpr int Q_N = 32;
static constexpr int F_N = 256;        // F_DIM == OUT_DIM == 256
static constexpr int SLOT_STRIDE = 40; // max degree slots (Poisson mean 6.4)
static constexpr int NWV = (F_N * F_N) / 4;      // 16,384 vec4s of W
static constexpr int T_TILES = E_N / 8;          // 1250 edge-tiles (8 edges)
static constexpr int LDS_STRIDE = 264;           // 256 + 8 pad

// prep: all 2048 blocks convert X (us8 chunks); first 512 blocks also do a
// short prologue (16 -> W convert, 496 -> bucket build).
static constexpr int PREP_GRID = 2048;
static constexpr int NT8 = PREP_GRID * 256;      // 524,288 threads
static constexpr int NXC = V_N * F_N * 2 / 8;    // 3,200,000 us8 chunks of X
static constexpr int HALF_NXC = NXC / 2;         // 1,600,000 per batch
static constexpr int WBLK = 16;
static constexpr int BBLK = 512 - WBLK;          // 496 bucket blocks

typedef unsigned short us;
typedef float f32x4 __attribute__((ext_vector_type(4)));
typedef us us4 __attribute__((ext_vector_type(4)));
typedef us us8 __attribute__((ext_vector_type(8)));
typedef __bf16 bf16x8 __attribute__((ext_vector_type(8)));

__device__ __forceinline__ us f2b(float f) {
  unsigned x = __builtin_bit_cast(unsigned, f);
  x += 0x7fffu + ((x >> 16) & 1u);   // round-to-nearest-even
  return (us)(x >> 16);
}
__device__ __forceinline__ float b2f(us u) {
  unsigned x = ((unsigned)u) << 16;
  return __builtin_bit_cast(float, x);
}

// Convert us8-chunk k of X (8 consecutive floats) into Xb[v][b][f].
// chunk k: b = k >= HALF_NXC; r = k - b*HALF_NXC; v = r>>5; fc = r&31.
// Wave's 64 lanes: 32 consecutive fc within a v -> 512B contiguous store
// per 32-lane half (16B/lane). Plain (cached) loads: X stays partially
// L3-resident across iterations (round-0 FETCH=50.9MB < 102.4MB read).
__device__ __forceinline__ void chunkconv(const float* __restrict__ X,
                                          us* __restrict__ Xb, int k) {
  int b = (k >= HALF_NXC) ? 1 : 0;
  int r = k - b * HALF_NXC;
  f32x4 lo = ((const f32x4*)X)[2 * (size_t)k];
  f32x4 hi = ((const f32x4*)X)[2 * (size_t)k + 1];
  us8 o;
  #pragma unroll
  for (int j = 0; j < 4; ++j) { o[j] = f2b(lo[j]); o[4 + j] = f2b(hi[j]); }
  int v = r >> 5, fc = r & 31;
  ((us8*)Xb)[(size_t)v * 64 + b * 32 + fc] = o;
}

// ---- P0: fp32->bf16 staging of X,W + bucket-build --------------------------

__global__ __launch_bounds__(256) void k_prep_bucket(
    const float* __restrict__ X, const float* __restrict__ Wm,
    const int* __restrict__ en, us* __restrict__ Xb, us* __restrict__ Wb,
    int* __restrict__ cnt, int* __restrict__ slots) {
  const int bx = blockIdx.x;
  const int tx = (int)threadIdx.x;
  // ---- prologue: W convert (blocks 0..15) / bucket build (16..511) ----
  if (bx < WBLK) {
    const int tid = bx * 256 + tx;
    for (int i = tid; i < NWV; i += WBLK * 256) {
      f32x4 v = ((const f32x4*)Wm)[i];
      us4 o;
      #pragma unroll
      for (int j = 0; j < 4; ++j) o[j] = f2b(v[j]);
      ((us4*)Wb)[i] = o;
    }
  } else if (bx < 512) {
    const int tid = (bx - WBLK) * 256 + tx;
    for (int i = tid; i < E_N * Q_N; i += BBLK * 256) {
      int v = en[i];
      int pos = atomicAdd(&cnt[v], 1);
      if (pos < SLOT_STRIDE) slots[v * SLOT_STRIDE + pos] = i >> 5;  // edge id
    }
  }
  // ---- X conversion: ALL 2048 blocks, 4-way unrolled (8 loads in flight) ----
  const int tid = bx * 256 + tx;
  int k = tid;
  for (; k + 3 * NT8 < NXC; k += 4 * NT8) {
    chunkconv(X, Xb, k);
    chunkconv(X, Xb, k + NT8);
    chunkconv(X, Xb, k + 2 * NT8);
    chunkconv(X, Xb, k + 3 * NT8);
  }
  for (; k + NT8 < NXC; k += 2 * NT8) {
    chunkconv(X, Xb, k);
    chunkconv(X, Xb, k + NT8);
  }
  for (; k < NXC; k += NT8) chunkconv(X, Xb, k);
}

// ---- P1: fused edge-mean + GEMM. One 8-edge tile per 512-thread block. -----
// Wave w (0..7) aggregates edge 8t+w. Gather is an explicit 8-deep rolling
// register pipeline (us8 buf[8], static indices only): consume load q while
// q+1..q+7 are in flight and q+8 issues. Node id comes via readlane -> SGPR
// base (SALU address math, no ds_bpermute in the hot loop).
// LDS tile rows 0-7: batch0, rows 8-15: batch1. Stride 264.

__global__ __launch_bounds__(512) void k_agg_gemm(
    const us* __restrict__ Xb, const int* __restrict__ en,
    const us* __restrict__ Wb, us* __restrict__ Yb) {
  __shared__ us tile[16 * LDS_STRIDE];
  const int t = blockIdx.x;
  const int w = threadIdx.x >> 6;      // 0..7: edge within tile
  const int lane = threadIdx.x & 63;
  const int m = lane & 15;
  const int quad = lane >> 4;
  const int half = lane >> 5;          // batch
  const int col8 = (lane & 31) * 8;    // feature col (8 wide)

  const int e = t * 8 + w;
  int nq = en[e * Q_N + (lane & 31)];  // lanes 0-31 hold the 32 node ids
  const us* Xg = Xb + half * F_N + col8;   // per-lane part of the address
  float a[8] = {0, 0, 0, 0, 0, 0, 0, 0};
  us8 buf[8];
  #pragma unroll
  for (int q = 0; q < 8; ++q) {        // prologue: fill the pipeline
    int mv = __builtin_amdgcn_readlane(nq, q);
    buf[q] = *(const us8*)(Xg + (size_t)mv * (2 * F_N));
  }
  #pragma unroll
  for (int q = 0; q < 24; ++q) {       // steady state: 8 loads in flight
    us8 v = buf[q & 7];
    int mv = __builtin_amdgcn_readlane(nq, q + 8);
    buf[q & 7] = *(const us8*)(Xg + (size_t)mv * (2 * F_N));
    #pragma unroll
    for (int j = 0; j < 8; ++j) a[j] += b2f(v[j]);
  }
  #pragma unroll
  for (int q = 24; q < 32; ++q) {      // drain
    us8 v = buf[q & 7];
    #pragma unroll
    for (int j = 0; j < 8; ++j) a[j] += b2f(v[j]);
  }
  const float sc = 1.0f / 32.0f;
  us8 o;
  #pragma unroll
  for (int j = 0; j < 8; ++j) o[j] = f2b(a[j] * sc);
  *(us8*)(tile + (w + 8 * half) * LDS_STRIDE + col8) = o;
  __syncthreads();

  // A-fragments from LDS (reused across this wave's 2 n-tiles)
  bf16x8 af[8];
  #pragma unroll
  for (int kk = 0; kk < 8; ++kk)
    af[kk] = *(const bf16x8*)(tile + m * LDS_STRIDE + quad * 8 + kk * 32);
  #pragma unroll
  for (int i = 0; i < 2; ++i) {
    const int nt = w * 2 + i;
    const us* bp = Wb + (size_t)(nt * 16 + m) * F_N + quad * 8;
    f32x4 acc = {0.f, 0.f, 0.f, 0.f};
    #pragma unroll
    for (int kk = 0; kk < 8; ++kk) {
      bf16x8 bv = *(const bf16x8*)(bp + kk * 32);
      acc = __builtin_amdgcn_mfma_f32_16x16x32_bf16(af[kk], bv, acc, 0, 0, 0);
    }
    #pragma unroll
    for (int r2 = 0; r2 < 4; ++r2) {
      int dr = quad * 4 + r2;            // D row within 16-row tile
      int e2 = t * 8 + (dr & 7);
      int b = dr >> 3;
      Yb[((size_t)e2 * 2 + b) * 256 + nt * 16 + m] = f2b(acc[r2]);  // [e][b][f]
    }
  }
}

// ---- P2: out[b,v,:] = bias + (1/deg) * sum_{e in slots(v)} Y[e,b,:] --------
// Yb [e][b][f]: each per-slot read is ONE coalesced 1KB wave load.

__global__ __launch_bounds__(256) void k_out(
    const us* __restrict__ Yb, const int* __restrict__ cnt,
    const int* __restrict__ slots, const float* __restrict__ bias,
    float* __restrict__ out) {
  const int w = threadIdx.x >> 6;
  const int lane = threadIdx.x & 63;
  const int v = blockIdx.x * 4 + w;
  const int half = lane >> 5;          // batch
  const int col8 = (lane & 31) * 8;
  int c = cnt[v];
  if (c > SLOT_STRIDE) c = SLOT_STRIDE;
  const int* sb = slots + (size_t)v * SLOT_STRIDE;
  const us* Yg = Yb + half * 256 + col8;
  float acc[8] = {0, 0, 0, 0, 0, 0, 0, 0};
  int j = 0;
  for (; j + 4 <= c; j += 4) {
    int ea = sb[j], eb = sb[j + 1], ec = sb[j + 2], ed = sb[j + 3];
    us8 pa = *(const us8*)(Yg + (size_t)ea * 512);
    us8 pb = *(const us8*)(Yg + (size_t)eb * 512);
    us8 pc = *(const us8*)(Yg + (size_t)ec * 512);
    us8 pd = *(const us8*)(Yg + (size_t)ed * 512);
    #pragma unroll
    for (int k = 0; k < 8; ++k)
      acc[k] += (b2f(pa[k]) + b2f(pb[k])) + (b2f(pc[k]) + b2f(pd[k]));
  }
  for (; j < c; ++j) {
    int e = sb[j];
    us8 p = *(const us8*)(Yg + (size_t)e * 512);
    #pragma unroll
    for (int k = 0; k < 8; ++k) acc[k] += b2f(p[k]);
  }
  float inv = 1.0f / (float)(c > 0 ? c : 1);
  f32x4 b0 = *(const f32x4*)(bias + col8);
  f32x4 b1 = *(const f32x4*)(bias + col8 + 4);
  f32x4 r0, r1;
  #pragma unroll
  for (int k = 0; k < 4; ++k) {
    r0[k] = b0[k] + acc[k] * inv;
    r1[k] = b1[k] + acc[4 + k] * inv;
  }
  float* op = out + ((size_t)half * V_N + v) * 256 + col8;
  __builtin_nontemporal_store(r0, (f32x4*)op);       // streaming, never re-read
  __builtin_nontemporal_store(r1, (f32x4*)(op + 4));
}

// ---- launch -----------------------------------------------------------------

extern "C" void kernel_launch(void* const* d_in, const int* in_sizes, int n_in,
                              void* d_out, int out_size, void* d_ws, size_t ws_size,
                              hipStream_t stream) {
  (void)in_sizes; (void)n_in; (void)out_size; (void)ws_size;
  const float* X = (const float*)d_in[0];    // (B,V,F) fp32
  const int* en = (const int*)d_in[1];       // (E,Q) int32
  const float* Wm = (const float*)d_in[2];   // (OUT,F) fp32
  const float* bias = (const float*)d_in[3]; // (OUT,) fp32
  float* out = (float*)d_out;                // (B,V,OUT) fp32

  char* ws = (char*)d_ws;
  int* cnt   = (int*)(ws);                    // V ints = 200,000 B
  int* slots = (int*)(ws + (1u << 20));       // V*40 ints = 8,000,000 B
  us*  Wb    = (us*)(ws + (10u << 20));       // 256*256 bf16 = 131,072 B
  us*  Yb    = (us*)(ws + (11u << 20));       // 2E*256 bf16 = 10,240,000 B
  us*  Xb    = (us*)(ws + (22u << 20));       // B*V*F bf16 = 51,200,000 B

  hipMemsetAsync(cnt, 0, V_N * sizeof(int), stream);
  k_prep_bucket<<<PREP_GRID, 256, 0, stream>>>(X, Wm, en, Xb, Wb, cnt, slots);
  k_agg_gemm<<<T_TILES, 512, 0, stream>>>(Xb, en, Wb, Yb);
  k_out<<<V_N / 4, 256, 0, stream>>>(Yb, cnt, slots, bias, out);
}

// Round 8
// 298.248 us; speedup vs baseline: 1.0059x; 1.0059x over previous
//
#include <hip/hip_runtime.h>
#include <hip/hip_bf16.h>
#include <stdint.h>

// Problem constants (from reference)
static constexpr int V_N = 50000;
static constexpr int E_N = 10000;
static constexpr int Q_N = 32;
static constexpr int F_N = 256;        // F_DIM == OUT_DIM == 256
static constexpr int SLOT_STRIDE = 40; // max degree slots (Poisson mean 6.4)
static constexpr int VF4 = V_N * F_N / 4;        // 3,200,000 f32x4 per batch
static constexpr int NXV = 2 * VF4;              // 6,400,000 f32x4 of X
static constexpr int NWV = (F_N * F_N) / 4;      // 16,384 vec4s of W
static constexpr int T_TILES = E_N / 8;          // 1250 edge-tiles (8 edges)
static constexpr int LDS_STRIDE = 264;           // 256 + 8 pad

// prep: all 2048 blocks convert X; first 512 blocks run a short prologue
// (16 -> W convert, 496 -> bucket build).
static constexpr int PREP_GRID = 2048;
static constexpr int NT = PREP_GRID * 256;       // 524,288 threads
static constexpr int WBLK = 16;
static constexpr int BBLK = 512 - WBLK;          // 496 bucket blocks

typedef unsigned short us;
typedef float f32x4 __attribute__((ext_vector_type(4)));
typedef us us4 __attribute__((ext_vector_type(4)));
typedef us us8 __attribute__((ext_vector_type(8)));
typedef __bf16 bf16x8 __attribute__((ext_vector_type(8)));

__device__ __forceinline__ us f2b(float f) {
  unsigned x = __builtin_bit_cast(unsigned, f);
  x += 0x7fffu + ((x >> 16) & 1u);   // round-to-nearest-even
  return (us)(x >> 16);
}
__device__ __forceinline__ float b2f(us u) {
  unsigned x = ((unsigned)u) << 16;
  return __builtin_bit_cast(float, x);
}
__device__ __forceinline__ us4 cvt4(f32x4 v) {
  us4 o;
  #pragma unroll
  for (int j = 0; j < 4; ++j) o[j] = f2b(v[j]);
  return o;
}

// f32x4 index i over X[b][v][f]  ->  us4 index into Xb[v][b][f].
// Lane-consecutive i => dense 512B wave stores (one full v-row half).
__device__ __forceinline__ int xidx4(int i) {
  int b = (i >= VF4) ? 1 : 0;
  int r = i - b * VF4;
  return ((r >> 6) << 7) + (b << 6) + (r & 63);
}

// ---- P0: fp32->bf16 staging of X,W + bucket-build --------------------------
// X conversion: dense f32x4 loads, explicitly batched 8-deep BEFORE any
// store (8 x 1KB wave-loads in flight; no strided footprint, no
// load/store interleave for the compiler to serialize).

__global__ __launch_bounds__(256) void k_prep_bucket(
    const float* __restrict__ X, const float* __restrict__ Wm,
    const int* __restrict__ en, us* __restrict__ Xb, us* __restrict__ Wb,
    int* __restrict__ cnt, int* __restrict__ slots) {
  const int bx = blockIdx.x;
  const int tx = (int)threadIdx.x;
  // ---- prologue: W convert (blocks 0..15) / bucket build (16..511) ----
  if (bx < WBLK) {
    const int tid = bx * 256 + tx;
    for (int i = tid; i < NWV; i += WBLK * 256) {
      ((us4*)Wb)[i] = cvt4(((const f32x4*)Wm)[i]);
    }
  } else if (bx < 512) {
    const int tid = (bx - WBLK) * 256 + tx;
    for (int i = tid; i < E_N * Q_N; i += BBLK * 256) {
      int v = en[i];
      int pos = atomicAdd(&cnt[v], 1);
      if (pos < SLOT_STRIDE) slots[v * SLOT_STRIDE + pos] = i >> 5;  // edge id
    }
  }
  // ---- X conversion: ALL 2048 blocks ----
  const int tid = bx * 256 + tx;
  const f32x4* X4 = (const f32x4*)X;
  us4* Xb4 = (us4*)Xb;
  // batch of 8 (covers chunks [0, 8*NT) = 4,194,304)
  {
    const int k = tid;
    f32x4 v0 = X4[k];
    f32x4 v1 = X4[k + NT];
    f32x4 v2 = X4[k + 2 * NT];
    f32x4 v3 = X4[k + 3 * NT];
    f32x4 v4 = X4[k + 4 * NT];
    f32x4 v5 = X4[k + 5 * NT];
    f32x4 v6 = X4[k + 6 * NT];
    f32x4 v7 = X4[k + 7 * NT];
    Xb4[xidx4(k)] = cvt4(v0);
    Xb4[xidx4(k + NT)] = cvt4(v1);
    Xb4[xidx4(k + 2 * NT)] = cvt4(v2);
    Xb4[xidx4(k + 3 * NT)] = cvt4(v3);
    Xb4[xidx4(k + 4 * NT)] = cvt4(v4);
    Xb4[xidx4(k + 5 * NT)] = cvt4(v5);
    Xb4[xidx4(k + 6 * NT)] = cvt4(v6);
    Xb4[xidx4(k + 7 * NT)] = cvt4(v7);
  }
  // batch of 4 (covers chunks [8*NT, 12*NT) = up to 6,291,456)
  {
    const int k = tid + 8 * NT;
    f32x4 v0 = X4[k];
    f32x4 v1 = X4[k + NT];
    f32x4 v2 = X4[k + 2 * NT];
    f32x4 v3 = X4[k + 3 * NT];
    Xb4[xidx4(k)] = cvt4(v0);
    Xb4[xidx4(k + NT)] = cvt4(v1);
    Xb4[xidx4(k + 2 * NT)] = cvt4(v2);
    Xb4[xidx4(k + 3 * NT)] = cvt4(v3);
  }
  // tail (chunks [12*NT, NXV) = 108,544 chunks)
  {
    const int k = tid + 12 * NT;
    if (k < NXV) Xb4[xidx4(k)] = cvt4(X4[k]);
  }
}

// ---- P1: fused edge-mean + GEMM. One 8-edge tile per 512-thread block. -----
// Wave w (0..7) aggregates edge 8t+w. Gather is an explicit 8-deep rolling
// register pipeline (us8 buf[8], static indices only): consume load q while
// q+1..q+7 are in flight and q+8 issues. Node id comes via readlane -> SGPR
// base (SALU address math, no ds_bpermute in the hot loop).
// LDS tile rows 0-7: batch0, rows 8-15: batch1. Stride 264.

__global__ __launch_bounds__(512) void k_agg_gemm(
    const us* __restrict__ Xb, const int* __restrict__ en,
    const us* __restrict__ Wb, us* __restrict__ Yb) {
  __shared__ us tile[16 * LDS_STRIDE];
  const int t = blockIdx.x;
  const int w = threadIdx.x >> 6;      // 0..7: edge within tile
  const int lane = threadIdx.x & 63;
  const int m = lane & 15;
  const int quad = lane >> 4;
  const int half = lane >> 5;          // batch
  const int col8 = (lane & 31) * 8;    // feature col (8 wide)

  const int e = t * 8 + w;
  int nq = en[e * Q_N + (lane & 31)];  // lanes 0-31 hold the 32 node ids
  const us* Xg = Xb + half * F_N + col8;   // per-lane part of the address
  float a[8] = {0, 0, 0, 0, 0, 0, 0, 0};
  us8 buf[8];
  #pragma unroll
  for (int q = 0; q < 8; ++q) {        // prologue: fill the pipeline
    int mv = __builtin_amdgcn_readlane(nq, q);
    buf[q] = *(const us8*)(Xg + (size_t)mv * (2 * F_N));
  }
  #pragma unroll
  for (int q = 0; q < 24; ++q) {       // steady state: 8 loads in flight
    us8 v = buf[q & 7];
    int mv = __builtin_amdgcn_readlane(nq, q + 8);
    buf[q & 7] = *(const us8*)(Xg + (size_t)mv * (2 * F_N));
    #pragma unroll
    for (int j = 0; j < 8; ++j) a[j] += b2f(v[j]);
  }
  #pragma unroll
  for (int q = 24; q < 32; ++q) {      // drain
    us8 v = buf[q & 7];
    #pragma unroll
    for (int j = 0; j < 8; ++j) a[j] += b2f(v[j]);
  }
  const float sc = 1.0f / 32.0f;
  us8 o;
  #pragma unroll
  for (int j = 0; j < 8; ++j) o[j] = f2b(a[j] * sc);
  *(us8*)(tile + (w + 8 * half) * LDS_STRIDE + col8) = o;
  __syncthreads();

  // A-fragments from LDS (reused across this wave's 2 n-tiles)
  bf16x8 af[8];
  #pragma unroll
  for (int kk = 0; kk < 8; ++kk)
    af[kk] = *(const bf16x8*)(tile + m * LDS_STRIDE + quad * 8 + kk * 32);
  #pragma unroll
  for (int i = 0; i < 2; ++i) {
    const int nt = w * 2 + i;
    const us* bp = Wb + (size_t)(nt * 16 + m) * F_N + quad * 8;
    f32x4 acc = {0.f, 0.f, 0.f, 0.f};
    #pragma unroll
    for (int kk = 0; kk < 8; ++kk) {
      bf16x8 bv = *(const bf16x8*)(bp + kk * 32);
      acc = __builtin_amdgcn_mfma_f32_16x16x32_bf16(af[kk], bv, acc, 0, 0, 0);
    }
    #pragma unroll
    for (int r2 = 0; r2 < 4; ++r2) {
      int dr = quad * 4 + r2;            // D row within 16-row tile
      int e2 = t * 8 + (dr & 7);
      int b = dr >> 3;
      Yb[((size_t)e2 * 2 + b) * 256 + nt * 16 + m] = f2b(acc[r2]);  // [e][b][f]
    }
  }
}

// ---- P2: out[b,v,:] = bias + (1/deg) * sum_{e in slots(v)} Y[e,b,:] --------
// Yb [e][b][f]: each per-slot read is ONE coalesced 1KB wave load.

__global__ __launch_bounds__(256) void k_out(
    const us* __restrict__ Yb, const int* __restrict__ cnt,
    const int* __restrict__ slots, const float* __restrict__ bias,
    float* __restrict__ out) {
  const int w = threadIdx.x >> 6;
  const int lane = threadIdx.x & 63;
  const int v = blockIdx.x * 4 + w;
  const int half = lane >> 5;          // batch
  const int col8 = (lane & 31) * 8;
  int c = cnt[v];
  if (c > SLOT_STRIDE) c = SLOT_STRIDE;
  const int* sb = slots + (size_t)v * SLOT_STRIDE;
  const us* Yg = Yb + half * 256 + col8;
  float acc[8] = {0, 0, 0, 0, 0, 0, 0, 0};
  int j = 0;
  for (; j + 4 <= c; j += 4) {
    int ea = sb[j], eb = sb[j + 1], ec = sb[j + 2], ed = sb[j + 3];
    us8 pa = *(const us8*)(Yg + (size_t)ea * 512);
    us8 pb = *(const us8*)(Yg + (size_t)eb * 512);
    us8 pc = *(const us8*)(Yg + (size_t)ec * 512);
    us8 pd = *(const us8*)(Yg + (size_t)ed * 512);
    #pragma unroll
    for (int k = 0; k < 8; ++k)
      acc[k] += (b2f(pa[k]) + b2f(pb[k])) + (b2f(pc[k]) + b2f(pd[k]));
  }
  for (; j < c; ++j) {
    int e = sb[j];
    us8 p = *(const us8*)(Yg + (size_t)e * 512);
    #pragma unroll
    for (int k = 0; k < 8; ++k) acc[k] += b2f(p[k]);
  }
  float inv = 1.0f / (float)(c > 0 ? c : 1);
  f32x4 b0 = *(const f32x4*)(bias + col8);
  f32x4 b1 = *(const f32x4*)(bias + col8 + 4);
  f32x4 r0, r1;
  #pragma unroll
  for (int k = 0; k < 4; ++k) {
    r0[k] = b0[k] + acc[k] * inv;
    r1[k] = b1[k] + acc[4 + k] * inv;
  }
  float* op = out + ((size_t)half * V_N + v) * 256 + col8;
  __builtin_nontemporal_store(r0, (f32x4*)op);       // streaming, never re-read
  __builtin_nontemporal_store(r1, (f32x4*)(op + 4));
}

// ---- launch -----------------------------------------------------------------

extern "C" void kernel_launch(void* const* d_in, const int* in_sizes, int n_in,
                              void* d_out, int out_size, void* d_ws, size_t ws_size,
                              hipStream_t stream) {
  (void)in_sizes; (void)n_in; (void)out_size; (void)ws_size;
  const float* X = (const float*)d_in[0];    // (B,V,F) fp32
  const int* en = (const int*)d_in[1];       // (E,Q) int32
  const float* Wm = (const float*)d_in[2];   // (OUT,F) fp32
  const float* bias = (const float*)d_in[3]; // (OUT,) fp32
  float* out = (float*)d_out;                // (B,V,OUT) fp32

  char* ws = (char*)d_ws;
  int* cnt   = (int*)(ws);                    // V ints = 200,000 B
  int* slots = (int*)(ws + (1u << 20));       // V*40 ints = 8,000,000 B
  us*  Wb    = (us*)(ws + (10u << 20));       // 256*256 bf16 = 131,072 B
  us*  Yb    = (us*)(ws + (11u << 20));       // 2E*256 bf16 = 10,240,000 B
  us*  Xb    = (us*)(ws + (22u << 20));       // B*V*F bf16 = 51,200,000 B

  hipMemsetAsync(cnt, 0, V_N * sizeof(int), stream);
  k_prep_bucket<<<PREP_GRID, 256, 0, stream>>>(X, Wm, en, Xb, Wb, cnt, slots);
  k_agg_gemm<<<T_TILES, 512, 0, stream>>>(Xb, en, Wb, Yb);
  k_out<<<V_N / 4, 256, 0, stream>>>(Yb, cnt, slots, bias, out);
}